// Round 4
// baseline (252.940 us; speedup 1.0000x reference)
//
#include <hip/hip_runtime.h>

// TTTConv: fused RMSNorm + depthwise causal conv1d (K=4), f32 in / f32 out.
// B=4, S=4096, H=2048.
// R3: two-pass, ZERO barriers. R0/R1 showed a barrier-synced block convoy
// stuck at 2.6 TB/s regardless of rows-per-barrier; hipcc drains vmcnt(0)
// before s_barrier so prefetch never survives. Pass 1: wave-per-row scale
// compute (pure stream). Pass 2: barrier-free norm+conv (x re-read is L3-warm).

#define BQ 4
#define SQ 4096
#define HQ 2048
#define KQ 4
#define ROWS (BQ * SQ)      // 16384
#define TROWS 32            // output s-rows per block in pass 2
#define NT2 512             // pass-2 threads: 512 * float4 = 2048 = H

typedef float f32x4 __attribute__((ext_vector_type(4)));

// ---------------- Pass 1: per-row RMS scale -> d_ws ----------------
// One wave per row. 8 float4 loads/lane cover H=2048. No LDS, no barriers.
__global__ __launch_bounds__(256) void ttt_scale_kernel(
    const float* __restrict__ x,     // [ROWS, H]
    float* __restrict__ sc)          // [ROWS]
{
    const int lane = threadIdx.x & 63;
    const int row  = blockIdx.x * 4 + (threadIdx.x >> 6);

    const float* xr = x + (size_t)row * HQ + lane * 4;

    float4 v[8];
    #pragma unroll
    for (int i = 0; i < 8; ++i)
        v[i] = *reinterpret_cast<const float4*>(xr + i * 256);

    float p = 0.f;
    #pragma unroll
    for (int i = 0; i < 8; ++i)
        p += v[i].x * v[i].x + v[i].y * v[i].y + v[i].z * v[i].z + v[i].w * v[i].w;

    #pragma unroll
    for (int off = 32; off >= 1; off >>= 1)
        p += __shfl_xor(p, off, 64);

    if (lane == 0)
        sc[row] = rsqrtf(p * (1.0f / HQ) + 1e-6f);
}

// ---------------- Pass 2: normalize + causal conv + store ----------------
// Thread owns 4 channels, 32-row strip. No barriers, no reductions.
__global__ __launch_bounds__(NT2) void ttt_conv_kernel(
    const float* __restrict__ x,      // [B,S,H]
    const float* __restrict__ gamma,  // [H]
    const float* __restrict__ cwp,    // [H,1,K]
    const float* __restrict__ cbp,    // [H]
    const float* __restrict__ sc,     // [ROWS] per-row scales
    float* __restrict__ out)          // [B,S,H]
{
    const int tid = threadIdx.x;
    const int tilesPerB = SQ / TROWS;
    const int b  = blockIdx.x / tilesPerB;
    const int s0 = (blockIdx.x % tilesPerB) * TROWS;
    const int h4 = tid * 4;

    const float4 g4    = *reinterpret_cast<const float4*>(gamma + h4);
    const float4 bias4 = *reinterpret_cast<const float4*>(cbp + h4);
    // conv_weight [H,1,K], K=4 -> one float4 per channel; transpose to taps,
    // then fold gamma into each tap (o = bias + sum_k (c_k*g) * (x*scale)).
    const float4 r0 = *reinterpret_cast<const float4*>(cwp + (size_t)(h4 + 0) * KQ);
    const float4 r1 = *reinterpret_cast<const float4*>(cwp + (size_t)(h4 + 1) * KQ);
    const float4 r2 = *reinterpret_cast<const float4*>(cwp + (size_t)(h4 + 2) * KQ);
    const float4 r3 = *reinterpret_cast<const float4*>(cwp + (size_t)(h4 + 3) * KQ);
    float4 c0 = make_float4(r0.x * g4.x, r1.x * g4.y, r2.x * g4.z, r3.x * g4.w);
    float4 c1 = make_float4(r0.y * g4.x, r1.y * g4.y, r2.y * g4.z, r3.y * g4.w);
    float4 c2 = make_float4(r0.z * g4.x, r1.z * g4.y, r2.z * g4.z, r3.z * g4.w);
    float4 c3 = make_float4(r0.w * g4.x, r1.w * g4.y, r2.w * g4.z, r3.w * g4.w);

    const float* xb  = x   + (size_t)b * SQ * HQ + h4;
    float*       ob  = out + (size_t)b * SQ * HQ + h4;
    const float* scb = sc  + (size_t)b * SQ;

    const float4 f4z = make_float4(0.f, 0.f, 0.f, 0.f);
    // window of scaled rows (x*scale): wm3 = s-3 (oldest) .. wm1 = s-1
    float4 wm3 = f4z, wm2 = f4z, wm1 = f4z;

    // halo preload: rows s0-3 .. s0-1
    #pragma unroll
    for (int k = 0; k < 3; ++k) {
        const int s = s0 - 3 + k;
        float4 w = f4z;
        if (s >= 0) {
            const float4 xv = *reinterpret_cast<const float4*>(xb + (size_t)s * HQ);
            const float sv = scb[s];
            w.x = xv.x * sv; w.y = xv.y * sv; w.z = xv.z * sv; w.w = xv.w * sv;
        }
        if (k == 0) wm3 = w; else if (k == 1) wm2 = w; else wm1 = w;
    }

    // prefetch group 0
    float4 buf[4];
    float4 scn;
    #pragma unroll
    for (int r = 0; r < 4; ++r)
        buf[r] = *reinterpret_cast<const float4*>(xb + (size_t)(s0 + r) * HQ);
    scn = *reinterpret_cast<const float4*>(scb + s0);

    for (int g = 0; g < TROWS / 4; ++g) {
        const int base = s0 + g * 4;

        float4 cur[4];
        #pragma unroll
        for (int r = 0; r < 4; ++r) cur[r] = buf[r];
        const float4 scv = scn;

        if (g + 1 < TROWS / 4) {   // prefetch next group (no barrier in the way)
            const int nb = base + 4;
            #pragma unroll
            for (int r = 0; r < 4; ++r)
                buf[r] = *reinterpret_cast<const float4*>(xb + (size_t)(nb + r) * HQ);
            scn = *reinterpret_cast<const float4*>(scb + nb);
        }

        const float svs[4] = { scv.x, scv.y, scv.z, scv.w };
        #pragma unroll
        for (int r = 0; r < 4; ++r) {
            const float sv = svs[r];
            float4 xn;
            xn.x = cur[r].x * sv; xn.y = cur[r].y * sv;
            xn.z = cur[r].z * sv; xn.w = cur[r].w * sv;

            f32x4 o;
            o.x = bias4.x + c0.x * wm3.x + c1.x * wm2.x + c2.x * wm1.x + c3.x * xn.x;
            o.y = bias4.y + c0.y * wm3.y + c1.y * wm2.y + c2.y * wm1.y + c3.y * xn.y;
            o.z = bias4.z + c0.z * wm3.z + c1.z * wm2.z + c2.z * wm1.z + c3.z * xn.z;
            o.w = bias4.w + c0.w * wm3.w + c1.w * wm2.w + c2.w * wm1.w + c3.w * xn.w;
            __builtin_nontemporal_store(
                o, reinterpret_cast<f32x4*>(ob + (size_t)(base + r) * HQ));

            wm3 = wm2; wm2 = wm1; wm1 = xn;
        }
    }
}

extern "C" void kernel_launch(void* const* d_in, const int* in_sizes, int n_in,
                              void* d_out, int out_size, void* d_ws, size_t ws_size,
                              hipStream_t stream) {
    const float* x  = (const float*)d_in[0];  // hidden_states [B,S,H] f32
    const float* nw = (const float*)d_in[1];  // norm_weight [H] f32
    const float* cw = (const float*)d_in[2];  // conv_weight [H,1,K] f32
    const float* cb = (const float*)d_in[3];  // conv_bias [H] f32
    float* o  = (float*)d_out;
    float* sc = (float*)d_ws;                 // ROWS floats = 64 KB scratch

    ttt_scale_kernel<<<ROWS / 4, 256, 0, stream>>>(x, sc);
    ttt_conv_kernel<<<BQ * (SQ / TROWS), NT2, 0, stream>>>(x, nw, cw, cb, sc, o);
}